// Round 9
// baseline (1588.430 us; speedup 1.0000x reference)
//
#include <hip/hip_runtime.h>
#include <hip/hip_bf16.h>

// TreeLSTM on MI355X. B=256 trees, 256 leaves (depth 9), H=512, X=300, 5 classes.
// f32 I/O; bf16 MFMA compute; f32 cell state. Output f32 [256,511,5].
//
// R9: LDS-BW fix. A-frags loaded DIRECT from global (frag layout == row-major 16B/lane),
// B (weights) in frag-ordered LDS, BM=128 (8 row-tiles/wave) amortizes B reads.
// LDS bytes/MFMA: 750B (R7) -> 250B. Memory plan/logits from R7/R8 (proven).

typedef __bf16 bf16;
typedef bf16  bf16x8 __attribute__((ext_vector_type(8)));
typedef float f32x4  __attribute__((ext_vector_type(4)));

__device__ __forceinline__ float sigm(float x){ return 1.0f/(1.0f + __expf(-x)); }
__device__ __forceinline__ float tanh_f(float x){ return 1.0f - 2.0f/(__expf(2.0f*x)+1.0f); }

// ---- converts ----
__global__ void cvt_pad_w(const float* __restrict__ src, bf16* __restrict__ dst){
  const int row = blockIdx.x, c = threadIdx.x;   // 1536 x 320
  dst[row*320 + c] = (bf16)(c < 300 ? src[row*300 + c] : 0.f);
}
__global__ void cvt_emb(const float* __restrict__ src, bf16* __restrict__ dst){
  const int row = blockIdx.x, c = threadIdx.x;   // 32000 x 320
  dst[row*320 + c] = (bf16)(c < 300 ? src[(size_t)row*300 + c] : 0.f);
}
// pack U: rows 0..1535 = U_iou, rows 1536..2559 = U_f  -> Uall[2560][1024] bf16
__global__ void cvt_u(const float* __restrict__ Uiou, const float* __restrict__ Uf,
                      bf16* __restrict__ dst){
  const int i = blockIdx.x*256 + threadIdx.x;
  if (i < 2560*1024)
    dst[i] = (bf16)(i < 1536*1024 ? Uiou[i] : Uf[i - 1536*1024]);
}

// Frag-ordered B tile (64 cols x 32 k): thread t writes 16B slot t; slot t holds
// (col=(t>>6)*16+(t&15), k-octet=(t>>4)&3). Wave w reads its frag at w*512 + l*8.
// A-frag (16 rows x 32 k): lane l loads 16B at row (l&15), k-octet (l>>4) -- directly
// from row-major global memory: src + (row0 + (l&15))*ldk + ks*32 + ((l>>4)&3)*8.

// ---- leaf: x=embp[wordid]; iou = x @ W_iou^T + b; cell. BM=128, 3 gates. ----
__global__ __launch_bounds__(256, 2)
void leaf_kernel(const int* __restrict__ wordid, const bf16* __restrict__ embp,
                 const bf16* __restrict__ Wpad, const float* __restrict__ Wb,
                 bf16* __restrict__ hcur, float* __restrict__ ccur)
{
  __shared__ bf16 ldsB[3*2048];   // 12 KB
  const int t = threadIdx.x;
  const int mrow0 = blockIdx.x*128, nblk = blockIdx.y*64;
  const int l = t&63, w = t>>6, lane16 = t&15, quad = (t>>4)&3;
  const int srow = (t>>6)*16 + (t&15), skq = (t>>4)&3;

  const bf16* gB[3];
  #pragma unroll
  for(int g=0;g<3;g++) gB[g] = Wpad + (size_t)(g*512 + nblk + srow)*320 + skq*8;

  int wid[8];
  #pragma unroll
  for(int rt=0;rt<8;rt++) wid[rt] = wordid[mrow0 + rt*16 + lane16];

  f32x4 acc[3][8];
  const f32x4 zero = {0.f,0.f,0.f,0.f};
  #pragma unroll
  for(int g=0;g<3;g++){
    #pragma unroll
    for(int rt=0;rt<8;rt++) acc[g][rt]=zero;
  }

  { // stage iter 0
    bf16x8 sb[3];
    #pragma unroll
    for(int g=0;g<3;g++){ sb[g] = *(const bf16x8*)gB[g]; gB[g] += 32; }
    #pragma unroll
    for(int g=0;g<3;g++) *(bf16x8*)&ldsB[g*2048 + t*8] = sb[g];
  }
  __syncthreads();

  for (int ks=0; ks<10; ks++){
    bf16x8 sbn[3];
    if (ks < 9){
      #pragma unroll
      for(int g=0;g<3;g++){ sbn[g] = *(const bf16x8*)gB[g]; gB[g] += 32; }
    }
    bf16x8 bfr[3];
    #pragma unroll
    for(int g=0;g<3;g++) bfr[g] = *(const bf16x8*)&ldsB[g*2048 + w*512 + l*8];
    #pragma unroll
    for(int rt=0;rt<8;rt++){
      bf16x8 a = *(const bf16x8*)(embp + (size_t)wid[rt]*320 + ks*32 + quad*8);
      #pragma unroll
      for(int g=0;g<3;g++)
        acc[g][rt] = __builtin_amdgcn_mfma_f32_16x16x32_bf16(a, bfr[g], acc[g][rt], 0,0,0);
    }
    if (ks < 9){
      __syncthreads();
      #pragma unroll
      for(int g=0;g<3;g++) *(bf16x8*)&ldsB[g*2048 + t*8] = sbn[g];
      __syncthreads();
    }
  }

  const int j = nblk + w*16 + lane16;
  const float bi=Wb[j], bo=Wb[512+j], bu=Wb[1024+j];
  #pragma unroll
  for(int rt=0;rt<8;rt++){
    #pragma unroll
    for(int reg=0;reg<4;reg++){
      const int row = mrow0 + rt*16 + quad*4 + reg;   // C/D: row=quad*4+reg, col=lane16
      float iv=acc[0][rt][reg]+bi, ov=acc[1][rt][reg]+bo, uv=acc[2][rt][reg]+bu;
      float c = sigm(iv)*tanh_f(uv);
      float h = sigm(ov)*tanh_f(c);
      ccur[(size_t)row*512 + j] = c;
      hcur[(size_t)row*512 + j] = (bf16)h;
    }
  }
}

// ---- level: h_cat @ Uall^T (5 gates), full cell with c_f. BM=128. ----
__global__ __launch_bounds__(256, 2)
void level_kernel(const bf16* __restrict__ hprev, bf16* __restrict__ hcur,
                  const float* __restrict__ cprev, float* __restrict__ ccur,
                  const bf16* __restrict__ Uall, const float* __restrict__ Uioub,
                  const float* __restrict__ Ufb)
{
  __shared__ bf16 ldsB[5*2048];   // 20 KB
  const int t = threadIdx.x;
  const int mrow0 = blockIdx.x*128, nblk = blockIdx.y*64;
  const int l = t&63, w = t>>6, lane16 = t&15, quad = (t>>4)&3;
  const int srow = (t>>6)*16 + (t&15), skq = (t>>4)&3;

  const bf16* gB[5];
  #pragma unroll
  for(int g=0;g<5;g++) gB[g] = Uall + (size_t)(g*512 + nblk + srow)*1024 + skq*8;
  const bf16* gA = hprev + (size_t)(mrow0 + lane16)*1024 + quad*8;

  f32x4 acc[5][8];
  const f32x4 zero = {0.f,0.f,0.f,0.f};
  #pragma unroll
  for(int g=0;g<5;g++){
    #pragma unroll
    for(int rt=0;rt<8;rt++) acc[g][rt]=zero;
  }

  { // stage iter 0
    bf16x8 sb[5];
    #pragma unroll
    for(int g=0;g<5;g++){ sb[g] = *(const bf16x8*)gB[g]; gB[g] += 32; }
    #pragma unroll
    for(int g=0;g<5;g++) *(bf16x8*)&ldsB[g*2048 + t*8] = sb[g];
  }
  __syncthreads();

  for (int ks=0; ks<32; ks++){
    bf16x8 sbn[5];
    if (ks < 31){
      #pragma unroll
      for(int g=0;g<5;g++){ sbn[g] = *(const bf16x8*)gB[g]; gB[g] += 32; }
    }
    bf16x8 bfr[5];
    #pragma unroll
    for(int g=0;g<5;g++) bfr[g] = *(const bf16x8*)&ldsB[g*2048 + w*512 + l*8];
    #pragma unroll
    for(int rt=0;rt<8;rt++){
      bf16x8 a = *(const bf16x8*)(gA + (size_t)rt*16*1024 + ks*32);
      #pragma unroll
      for(int g=0;g<5;g++)
        acc[g][rt] = __builtin_amdgcn_mfma_f32_16x16x32_bf16(a, bfr[g], acc[g][rt], 0,0,0);
    }
    if (ks < 31){
      __syncthreads();
      #pragma unroll
      for(int g=0;g<5;g++) *(bf16x8*)&ldsB[g*2048 + t*8] = sbn[g];
      __syncthreads();
    }
  }

  const int j = nblk + w*16 + lane16;
  const float bi =Uioub[j], bo=Uioub[512+j], bu=Uioub[1024+j];
  const float bfl=Ufb[j],   bfr2=Ufb[512+j];
  #pragma unroll
  for(int rt=0;rt<8;rt++){
    #pragma unroll
    for(int reg=0;reg<4;reg++){
      const int row = mrow0 + rt*16 + quad*4 + reg;
      float iv=acc[0][rt][reg]+bi, ov=acc[1][rt][reg]+bo, uv=acc[2][rt][reg]+bu;
      float fl=acc[3][rt][reg]+bfl, fr=acc[4][rt][reg]+bfr2;
      float cl = cprev[((size_t)row*2  )*512 + j];
      float cr = cprev[((size_t)row*2+1)*512 + j];
      float cf = sigm(fl)*cl + sigm(fr)*cr;
      float c  = sigm(iv)*tanh_f(uv) + cf;
      float h  = sigm(ov)*tanh_f(c);
      ccur[(size_t)row*512 + j] = c;
      hcur[(size_t)row*512 + j] = (bf16)h;
    }
  }
}

// ---- logits: out[node*5+c] = h_row . lin_w[c] + lin_b[c] ----
__global__ __launch_bounds__(256)
void logits_kernel(const bf16* __restrict__ h, const float* __restrict__ linw,
                   const float* __restrict__ linb, float* __restrict__ out,
                   int rowbase, int lgm, int mask, int off){
  const int row = blockIdx.x*4 + (threadIdx.x>>6);
  const int l = threadIdx.x & 63;
  bf16x8 hv = *(const bf16x8*)(h + (size_t)row*512 + l*8);
  float hf[8];
  #pragma unroll
  for(int jj=0;jj<8;jj++) hf[jj] = (float)hv[jj];
  float s[5];
  #pragma unroll
  for(int c=0;c<5;c++){
    const f32x4 w0 = *(const f32x4*)(linw + c*512 + l*8);
    const f32x4 w1 = *(const f32x4*)(linw + c*512 + l*8 + 4);
    float a = 0.f;
    #pragma unroll
    for(int jj=0;jj<4;jj++) a += hf[jj]*w0[jj] + hf[4+jj]*w1[jj];
    s[c]=a;
  }
  #pragma unroll
  for(int o=32;o>0;o>>=1){
    #pragma unroll
    for(int c=0;c<5;c++) s[c] += __shfl_down(s[c], o, 64);
  }
  if (l==0){
    const int g = rowbase + row;
    const int node = (g>>lgm)*511 + off + (g&mask);
    #pragma unroll
    for(int c=0;c<5;c++) out[(size_t)node*5+c] = s[c] + linb[c];
  }
}

__global__ void zero_out(float* out, int n){
  int i = blockIdx.x*256 + threadIdx.x;
  if (i < n) out[i] = 0.f;
}

extern "C" void kernel_launch(void* const* d_in, const int* in_sizes, int n_in,
                              void* d_out, int out_size, void* d_ws, size_t ws_size,
                              hipStream_t stream)
{
  const int*   wordid = (const int*)d_in[0];
  const float* emb    = (const float*)d_in[1];
  const float* Wiou   = (const float*)d_in[2];
  const float* Wioub  = (const float*)d_in[3];
  const float* Uiou   = (const float*)d_in[4];
  const float* Uioub  = (const float*)d_in[5];
  const float* Uf     = (const float*)d_in[6];
  const float* Ufb    = (const float*)d_in[7];
  const float* linw   = (const float*)d_in[8];
  const float* linb   = (const float*)d_in[9];
  float* out = (float*)d_out;

  // ---- fixed-region layout (R7/R8) ----
  const size_t oWPD  = 0;
  const size_t oUALL = oWPD  + (size_t)1536*320*2;
  const size_t oEMB  = oUALL + (size_t)2560*1024*2;
  const size_t oH1   = oEMB  + (size_t)32000*320*2;
  const size_t oC1   = oH1   + (size_t)32768*512*2;
  const size_t oH0   = oC1   + (size_t)32768*512*4;
  size_t R0 = 0;
  {
    const size_t t4 = oH0 + (size_t)16384*512*(2+4);   // 177.7 MB
    const size_t t8 = oH0 + (size_t) 8192*512*(2+4);   // 152.5 MB
    if      (ws_size >= t4) R0 = 16384;
    else if (ws_size >= t8) R0 = 8192;
  }
  if (R0 == 0){
    zero_out<<<(out_size+255)/256, 256, 0, stream>>>(out, out_size);
    return;
  }

  char* ws = (char*)d_ws;
  bf16*  Wpad = (bf16*)(ws + oWPD);
  bf16*  Uall = (bf16*)(ws + oUALL);
  bf16*  embp = (bf16*)(ws + oEMB);
  bf16*  h1   = (bf16*)(ws + oH1);
  float* c1   = (float*)(ws + oC1);
  bf16*  h0   = (bf16*)(ws + oH0);
  float* c0   = (float*)(ws + oH0 + R0*1024);

  cvt_pad_w<<<1536, 320, 0, stream>>>(Wiou, Wpad);
  cvt_u<<<(2560*1024+255)/256, 256, 0, stream>>>(Uiou, Uf, Uall);
  cvt_emb<<<32000, 320, 0, stream>>>(emb, embp);

  const int offs[9] = {0,256,384,448,480,496,504,508,510};
  const int nchunk = (int)(65536 / R0);

  // ---- leaf + level-1, chunked through h0/c0 scratch ----
  for (int ch = 0; ch < nchunk; ch++){
    const int* wid = wordid + (size_t)ch*R0;
    leaf_kernel<<<dim3((int)(R0/128), 8), 256, 0, stream>>>(wid, embp, Wpad, Wioub, h0, c0);
    logits_kernel<<<(int)(R0/4), 256, 0, stream>>>(h0, linw, linb, out,
                                                   (int)(ch*R0), 8, 255, 0);
    bf16*  h1c = h1 + (size_t)ch*(R0/2)*512;
    float* c1c = c1 + (size_t)ch*(R0/2)*512;
    level_kernel<<<dim3((int)(R0/256), 8), 256, 0, stream>>>(h0, h1c, c0, c1c,
                                                             Uall, Uioub, Ufb);
  }
  logits_kernel<<<32768/4, 256, 0, stream>>>(h1, linw, linb, out, 0, 7, 127, offs[1]);

  // ---- levels 2..8: ping-pong h1/c1 <-> h0/c0 regions ----
  for (int lv = 2; lv <= 8; lv++){
    const int rows = 65536 >> lv;
    const bf16*  hin  = (lv & 1) ? h0 : h1;
    bf16*        hout = (lv & 1) ? h1 : h0;
    const float* cin  = (lv & 1) ? c0 : c1;
    float*       cout = (lv & 1) ? c1 : c0;
    level_kernel<<<dim3(rows/128, 8), 256, 0, stream>>>(hin, hout, cin, cout,
                                                        Uall, Uioub, Ufb);
    logits_kernel<<<rows/4, 256, 0, stream>>>(hout, linw, linb, out,
                                              0, 8-lv, (256>>lv)-1, offs[lv]);
  }
}

// Round 10
// 1297.693 us; speedup vs baseline: 1.2240x; 1.2240x over previous
//
#include <hip/hip_runtime.h>
#include <hip/hip_bf16.h>

// TreeLSTM on MI355X. B=256 trees, 256 leaves (depth 9), H=512, X=300, 5 classes.
// f32 I/O; bf16 MFMA compute; f32 cell state. Output f32 [256,511,5].
//
// R10 = R7 (best, 1038us) + register prefetch of next K-step's global loads
// (issued before the MFMA section so vmcnt-wait is covered by ~194cyc of MFMA)
// + fragment-ordered conflict-free LDS (R8's mapping, single 24KB buffer,
// 2 barriers/iter). Launcher/memory plan identical to R7.

typedef __bf16 bf16;
typedef bf16  bf16x8 __attribute__((ext_vector_type(8)));
typedef float f32x4  __attribute__((ext_vector_type(4)));

__device__ __forceinline__ float sigm(float x){ return 1.0f/(1.0f + __expf(-x)); }
__device__ __forceinline__ float tanh_f(float x){ return 1.0f - 2.0f/(__expf(2.0f*x)+1.0f); }

// ---- converts ----
__global__ void cvt_pad_w(const float* __restrict__ src, bf16* __restrict__ dst){
  const int row = blockIdx.x, c = threadIdx.x;   // 1536 x 320
  dst[row*320 + c] = (bf16)(c < 300 ? src[row*300 + c] : 0.f);
}
__global__ void cvt_emb(const float* __restrict__ src, bf16* __restrict__ dst){
  const int row = blockIdx.x, c = threadIdx.x;   // 32000 x 320
  dst[row*320 + c] = (bf16)(c < 300 ? src[(size_t)row*300 + c] : 0.f);
}
// pack U: rows 0..1535 = U_iou, rows 1536..2559 = U_f -> Uall[2560][1024] bf16
__global__ void cvt_u(const float* __restrict__ Uiou, const float* __restrict__ Uf,
                      bf16* __restrict__ dst){
  const int i = blockIdx.x*256 + threadIdx.x;
  if (i < 2560*1024)
    dst[i] = (bf16)(i < 1536*1024 ? Uiou[i] : Uf[i - 1536*1024]);
}

// Fragment-ordered LDS (verified R8/R9, 0 conflicts): 64x32 bf16 tile = 256 slots x 16B.
// Thread t stages slot t = (rt=t>>6, kq=(t>>4)&3, r16=t&15) <- global row rt*16+r16,
// k-octet kq. Reads: A rt -> tile + rt*512 + l*8 ; B wave w -> tile + w*512 + l*8.

// ---- leaf: x=embp[wordid]; iou = x @ W_iou^T + b; cell. ----
__global__ __launch_bounds__(256)
void leaf_kernel(const int* __restrict__ wordid, const bf16* __restrict__ embp,
                 const bf16* __restrict__ Wpad, const float* __restrict__ Wb,
                 bf16* __restrict__ hcur, float* __restrict__ ccur)
{
  __shared__ bf16 lds[4*2048];   // A + 3 gates = 16 KB
  const int t = threadIdx.x;
  const int mrow0 = blockIdx.x*64, nblk = blockIdx.y*64;
  const int l = t&63, w = t>>6, lane16 = t&15, quad = (t>>4)&3;
  const int srow = (t>>6)*16 + (t&15), skq = (t>>4)&3;

  const int wid = wordid[mrow0 + srow];
  const bf16* gp[4];
  gp[0] = embp + (size_t)wid*320 + skq*8;
  gp[1] = Wpad + (size_t)(       nblk + srow)*320 + skq*8;
  gp[2] = Wpad + (size_t)(512  + nblk + srow)*320 + skq*8;
  gp[3] = Wpad + (size_t)(1024 + nblk + srow)*320 + skq*8;

  f32x4 acc[3][4];
  const f32x4 zero = {0.f,0.f,0.f,0.f};
  #pragma unroll
  for(int o=0;o<3;o++){
    #pragma unroll
    for(int rt=0;rt<4;rt++) acc[o][rt]=zero;
  }

  { // prologue: stage k=0
    bf16x8 stg[4];
    #pragma unroll
    for(int i=0;i<4;i++){ stg[i] = *(const bf16x8*)gp[i]; gp[i] += 32; }
    #pragma unroll
    for(int i=0;i<4;i++) *(bf16x8*)&lds[i*2048 + t*8] = stg[i];
  }
  __syncthreads();

  for (int ks=0; ks<10; ks++){
    bf16x8 stg[4];
    if (ks < 9){            // prefetch k+1 BEFORE the MFMA section (latency covered)
      #pragma unroll
      for(int i=0;i<4;i++){ stg[i] = *(const bf16x8*)gp[i]; gp[i] += 32; }
    }
    bf16x8 bfr[3], a[4];
    #pragma unroll
    for(int g=0;g<3;g++) bfr[g] = *(const bf16x8*)&lds[(1+g)*2048 + w*512 + l*8];
    #pragma unroll
    for(int rt=0;rt<4;rt++) a[rt] = *(const bf16x8*)&lds[rt*512 + l*8];
    #pragma unroll
    for(int rt=0;rt<4;rt++){
      #pragma unroll
      for(int g=0;g<3;g++)
        acc[g][rt] = __builtin_amdgcn_mfma_f32_16x16x32_bf16(a[rt], bfr[g], acc[g][rt], 0,0,0);
    }
    if (ks < 9){
      __syncthreads();      // all reads of k done
      #pragma unroll
      for(int i=0;i<4;i++) *(bf16x8*)&lds[i*2048 + t*8] = stg[i];
      __syncthreads();      // writes of k+1 visible
    }
  }

  const int j = nblk + w*16 + lane16;
  const float bi=Wb[j], bo=Wb[512+j], bu=Wb[1024+j];
  #pragma unroll
  for(int rt=0;rt<4;rt++){
    #pragma unroll
    for(int reg=0;reg<4;reg++){
      const int row = mrow0 + rt*16 + quad*4 + reg;   // C/D: row=quad*4+reg, col=lane16
      float iv=acc[0][rt][reg]+bi, ov=acc[1][rt][reg]+bo, uv=acc[2][rt][reg]+bu;
      float c = sigm(iv)*tanh_f(uv);
      float h = sigm(ov)*tanh_f(c);
      ccur[(size_t)row*512 + j] = c;
      hcur[(size_t)row*512 + j] = (bf16)h;
    }
  }
}

// ---- level: h_cat @ Uall^T (5 gates), full cell with c_f. ----
__global__ __launch_bounds__(256)
void level_kernel(const bf16* __restrict__ hprev, bf16* __restrict__ hcur,
                  const float* __restrict__ cprev, float* __restrict__ ccur,
                  const bf16* __restrict__ Uall, const float* __restrict__ Uioub,
                  const float* __restrict__ Ufb)
{
  __shared__ bf16 lds[6*2048];   // A + 5 gates = 24 KB, single buffer
  const int t = threadIdx.x;
  const int mrow0 = blockIdx.x*64, nblk = blockIdx.y*64;
  const int l = t&63, w = t>>6, lane16 = t&15, quad = (t>>4)&3;
  const int srow = (t>>6)*16 + (t&15), skq = (t>>4)&3;

  const bf16* gp[6];
  gp[0] = hprev + (size_t)(mrow0 + srow)*1024 + skq*8;   // h_cat rows contiguous
  #pragma unroll
  for(int g=0;g<5;g++)
    gp[1+g] = Uall + (size_t)(g*512 + nblk + srow)*1024 + skq*8;

  f32x4 acc[5][4];
  const f32x4 zero = {0.f,0.f,0.f,0.f};
  #pragma unroll
  for(int o=0;o<5;o++){
    #pragma unroll
    for(int rt=0;rt<4;rt++) acc[o][rt]=zero;
  }

  { // prologue: stage k=0
    bf16x8 stg[6];
    #pragma unroll
    for(int i=0;i<6;i++){ stg[i] = *(const bf16x8*)gp[i]; gp[i] += 32; }
    #pragma unroll
    for(int i=0;i<6;i++) *(bf16x8*)&lds[i*2048 + t*8] = stg[i];
  }
  __syncthreads();

  for (int ks=0; ks<32; ks++){
    bf16x8 stg[6];
    if (ks < 31){           // prefetch k+1 before MFMA section
      #pragma unroll
      for(int i=0;i<6;i++){ stg[i] = *(const bf16x8*)gp[i]; gp[i] += 32; }
    }
    bf16x8 bfr[5], a[4];
    #pragma unroll
    for(int g=0;g<5;g++) bfr[g] = *(const bf16x8*)&lds[(1+g)*2048 + w*512 + l*8];
    #pragma unroll
    for(int rt=0;rt<4;rt++) a[rt] = *(const bf16x8*)&lds[rt*512 + l*8];
    #pragma unroll
    for(int rt=0;rt<4;rt++){
      #pragma unroll
      for(int g=0;g<5;g++)
        acc[g][rt] = __builtin_amdgcn_mfma_f32_16x16x32_bf16(a[rt], bfr[g], acc[g][rt], 0,0,0);
    }
    if (ks < 31){
      __syncthreads();
      #pragma unroll
      for(int i=0;i<6;i++) *(bf16x8*)&lds[i*2048 + t*8] = stg[i];
      __syncthreads();
    }
  }

  const int j = nblk + w*16 + lane16;
  const float bi =Uioub[j], bo=Uioub[512+j], bu=Uioub[1024+j];
  const float bfl=Ufb[j],   bfr2=Ufb[512+j];
  #pragma unroll
  for(int rt=0;rt<4;rt++){
    #pragma unroll
    for(int reg=0;reg<4;reg++){
      const int row = mrow0 + rt*16 + quad*4 + reg;
      float iv=acc[0][rt][reg]+bi, ov=acc[1][rt][reg]+bo, uv=acc[2][rt][reg]+bu;
      float fl=acc[3][rt][reg]+bfl, fr=acc[4][rt][reg]+bfr2;
      float cl = cprev[((size_t)row*2  )*512 + j];
      float cr = cprev[((size_t)row*2+1)*512 + j];
      float cf = sigm(fl)*cl + sigm(fr)*cr;
      float c  = sigm(iv)*tanh_f(uv) + cf;
      float h  = sigm(ov)*tanh_f(c);
      ccur[(size_t)row*512 + j] = c;
      hcur[(size_t)row*512 + j] = (bf16)h;
    }
  }
}

// ---- logits: out[node*5+c] = h_row . lin_w[c] + lin_b[c] ----
__global__ __launch_bounds__(256)
void logits_kernel(const bf16* __restrict__ h, const float* __restrict__ linw,
                   const float* __restrict__ linb, float* __restrict__ out,
                   int rowbase, int lgm, int mask, int off){
  const int row = blockIdx.x*4 + (threadIdx.x>>6);
  const int l = threadIdx.x & 63;
  bf16x8 hv = *(const bf16x8*)(h + (size_t)row*512 + l*8);
  float hf[8];
  #pragma unroll
  for(int jj=0;jj<8;jj++) hf[jj] = (float)hv[jj];
  float s[5];
  #pragma unroll
  for(int c=0;c<5;c++){
    const f32x4 w0 = *(const f32x4*)(linw + c*512 + l*8);
    const f32x4 w1 = *(const f32x4*)(linw + c*512 + l*8 + 4);
    float a = 0.f;
    #pragma unroll
    for(int jj=0;jj<4;jj++) a += hf[jj]*w0[jj] + hf[4+jj]*w1[jj];
    s[c]=a;
  }
  #pragma unroll
  for(int o=32;o>0;o>>=1){
    #pragma unroll
    for(int c=0;c<5;c++) s[c] += __shfl_down(s[c], o, 64);
  }
  if (l==0){
    const int g = rowbase + row;
    const int node = (g>>lgm)*511 + off + (g&mask);
    #pragma unroll
    for(int c=0;c<5;c++) out[(size_t)node*5+c] = s[c] + linb[c];
  }
}

__global__ void zero_out(float* out, int n){
  int i = blockIdx.x*256 + threadIdx.x;
  if (i < n) out[i] = 0.f;
}

extern "C" void kernel_launch(void* const* d_in, const int* in_sizes, int n_in,
                              void* d_out, int out_size, void* d_ws, size_t ws_size,
                              hipStream_t stream)
{
  const int*   wordid = (const int*)d_in[0];
  const float* emb    = (const float*)d_in[1];
  const float* Wiou   = (const float*)d_in[2];
  const float* Wioub  = (const float*)d_in[3];
  const float* Uiou   = (const float*)d_in[4];
  const float* Uioub  = (const float*)d_in[5];
  const float* Uf     = (const float*)d_in[6];
  const float* Ufb    = (const float*)d_in[7];
  const float* linw   = (const float*)d_in[8];
  const float* linb   = (const float*)d_in[9];
  float* out = (float*)d_out;

  // ---- fixed-region layout (R7) ----
  const size_t oWPD  = 0;
  const size_t oUALL = oWPD  + (size_t)1536*320*2;
  const size_t oEMB  = oUALL + (size_t)2560*1024*2;
  const size_t oH1   = oEMB  + (size_t)32000*320*2;
  const size_t oC1   = oH1   + (size_t)32768*512*2;
  const size_t oH0   = oC1   + (size_t)32768*512*4;
  size_t R0 = 0;
  {
    const size_t t4 = oH0 + (size_t)16384*512*(2+4);   // 177.7 MB
    const size_t t8 = oH0 + (size_t) 8192*512*(2+4);   // 152.5 MB
    if      (ws_size >= t4) R0 = 16384;
    else if (ws_size >= t8) R0 = 8192;
  }
  if (R0 == 0){
    zero_out<<<(out_size+255)/256, 256, 0, stream>>>(out, out_size);
    return;
  }

  char* ws = (char*)d_ws;
  bf16*  Wpad = (bf16*)(ws + oWPD);
  bf16*  Uall = (bf16*)(ws + oUALL);
  bf16*  embp = (bf16*)(ws + oEMB);
  bf16*  h1   = (bf16*)(ws + oH1);
  float* c1   = (float*)(ws + oC1);
  bf16*  h0   = (bf16*)(ws + oH0);
  float* c0   = (float*)(ws + oH0 + R0*1024);

  cvt_pad_w<<<1536, 320, 0, stream>>>(Wiou, Wpad);
  cvt_u<<<(2560*1024+255)/256, 256, 0, stream>>>(Uiou, Uf, Uall);
  cvt_emb<<<32000, 320, 0, stream>>>(emb, embp);

  const int offs[9] = {0,256,384,448,480,496,504,508,510};
  const int nchunk = (int)(65536 / R0);

  // ---- leaf + level-1, chunked through h0/c0 scratch ----
  for (int ch = 0; ch < nchunk; ch++){
    const int* wid = wordid + (size_t)ch*R0;
    leaf_kernel<<<dim3((int)(R0/64), 8), 256, 0, stream>>>(wid, embp, Wpad, Wioub, h0, c0);
    logits_kernel<<<(int)(R0/4), 256, 0, stream>>>(h0, linw, linb, out,
                                                   (int)(ch*R0), 8, 255, 0);
    bf16*  h1c = h1 + (size_t)ch*(R0/2)*512;
    float* c1c = c1 + (size_t)ch*(R0/2)*512;
    level_kernel<<<dim3((int)(R0/128), 8), 256, 0, stream>>>(h0, h1c, c0, c1c,
                                                             Uall, Uioub, Ufb);
  }
  logits_kernel<<<32768/4, 256, 0, stream>>>(h1, linw, linb, out, 0, 7, 127, offs[1]);

  // ---- levels 2..8: ping-pong h1/c1 <-> h0/c0 regions ----
  for (int lv = 2; lv <= 8; lv++){
    const int rows = 65536 >> lv;
    const bf16*  hin  = (lv & 1) ? h0 : h1;
    bf16*        hout = (lv & 1) ? h1 : h0;
    const float* cin  = (lv & 1) ? c0 : c1;
    float*       cout = (lv & 1) ? c1 : c0;
    level_kernel<<<dim3(rows/64, 8), 256, 0, stream>>>(hin, hout, cin, cout,
                                                       Uall, Uioub, Ufb);
    logits_kernel<<<rows/4, 256, 0, stream>>>(hout, linw, linb, out,
                                              0, 8-lv, (256>>lv)-1, offs[lv]);
  }
}

// Round 11
// 920.120 us; speedup vs baseline: 1.7263x; 1.4104x over previous
//
#include <hip/hip_runtime.h>
#include <hip/hip_bf16.h>

// TreeLSTM on MI355X. B=256 trees, 256 leaves (depth 9), H=512, C=5.
// f32 I/O; bf16 MFMA; f32 cell state. Output f32 [256,511,5].
//
// R11 = R7 (best, 1038us; its K-loop/LDS/staging proven best of 6 variants)
// + BM=128 level kernel (same staging pattern, A as two 64-row stride-40 tiles,
// acc[5][8], launch_bounds(256,2)) for big levels (lv1-4). lv5-8 + leaf keep
// the exact R7 bodies. Launcher/memory plan identical to R7.

typedef __bf16 bf16;
typedef bf16  bf16x8 __attribute__((ext_vector_type(8)));
typedef float f32x4  __attribute__((ext_vector_type(4)));

__device__ __forceinline__ float sigm(float x){ return 1.0f/(1.0f + __expf(-x)); }
__device__ __forceinline__ float tanh_f(float x){ return 1.0f - 2.0f/(__expf(2.0f*x)+1.0f); }

// ---- converts ----
__global__ void cvt_pad_w(const float* __restrict__ src, bf16* __restrict__ dst){
  const int row = blockIdx.x, c = threadIdx.x;   // 1536 x 320
  dst[row*320 + c] = (bf16)(c < 300 ? src[row*300 + c] : 0.f);
}
__global__ void cvt_emb(const float* __restrict__ src, bf16* __restrict__ dst){
  const int row = blockIdx.x, c = threadIdx.x;   // 32000 x 320
  dst[row*320 + c] = (bf16)(c < 300 ? src[(size_t)row*300 + c] : 0.f);
}
// pack U: rows 0..1535 = U_iou, rows 1536..2559 = U_f -> Uall[2560][1024] bf16
__global__ void cvt_u(const float* __restrict__ Uiou, const float* __restrict__ Uf,
                      bf16* __restrict__ dst){
  const int i = blockIdx.x*256 + threadIdx.x;
  if (i < 2560*1024)
    dst[i] = (bf16)(i < 1536*1024 ? Uiou[i] : Uf[i - 1536*1024]);
}

// ---- leaf (exact R7 body): x=embp[wordid]; iou = x @ W_iou^T + b; cell ----
__global__ __launch_bounds__(256)
void leaf_kernel(const int* __restrict__ wordid, const bf16* __restrict__ embp,
                 const bf16* __restrict__ Wpad, const float* __restrict__ Wb,
                 bf16* __restrict__ hcur, float* __restrict__ ccur)
{
  __shared__ bf16 lsA[64*40];      // stride 40 elems (80 B) — proven R4/R7 layout
  __shared__ bf16 lsB[3][64*40];
  const int t = threadIdx.x;
  const int mrow0 = blockIdx.x*64, nblk = blockIdx.y*64;
  const int r = t>>2, kc = (t&3)*8;
  const int lane16 = t&15, quad = (t&63)>>4, w = t>>6;

  f32x4 acc[3][4];
  const f32x4 zero = {0.f,0.f,0.f,0.f};
  #pragma unroll
  for(int o=0;o<3;o++){
    #pragma unroll
    for(int rt=0;rt<4;rt++) acc[o][rt]=zero;
  }

  const int wid = wordid[mrow0 + r];
  const bf16* arow = embp + (size_t)wid*320;
  const int col = nblk + r;
  for (int k0=0;k0<320;k0+=32){
    *(bf16x8*)&lsA[r*40+kc]    = *(const bf16x8*)&arow[k0+kc];
    *(bf16x8*)&lsB[0][r*40+kc] = *(const bf16x8*)&Wpad[(size_t)col*320        + k0+kc];
    *(bf16x8*)&lsB[1][r*40+kc] = *(const bf16x8*)&Wpad[(size_t)(512+col)*320  + k0+kc];
    *(bf16x8*)&lsB[2][r*40+kc] = *(const bf16x8*)&Wpad[(size_t)(1024+col)*320 + k0+kc];
    __syncthreads();
    bf16x8 bfrag[3];
    #pragma unroll
    for(int o=0;o<3;o++) bfrag[o] = *(const bf16x8*)&lsB[o][(w*16+lane16)*40 + quad*8];
    #pragma unroll
    for(int rt=0;rt<4;rt++){
      bf16x8 a = *(const bf16x8*)&lsA[(rt*16+lane16)*40 + quad*8];
      #pragma unroll
      for(int o=0;o<3;o++)
        acc[o][rt] = __builtin_amdgcn_mfma_f32_16x16x32_bf16(a, bfrag[o], acc[o][rt], 0,0,0);
    }
    __syncthreads();
  }
  const int j = nblk + w*16 + lane16;
  const float bi=Wb[j], bo=Wb[512+j], bu=Wb[1024+j];
  #pragma unroll
  for(int rt=0;rt<4;rt++){
    #pragma unroll
    for(int reg=0;reg<4;reg++){
      const int row = mrow0 + rt*16 + quad*4 + reg;   // C/D: row=quad*4+reg, col=lane16
      float iv=acc[0][rt][reg]+bi, ov=acc[1][rt][reg]+bo, uv=acc[2][rt][reg]+bu;
      float c = sigm(iv)*tanh_f(uv);
      float h = sigm(ov)*tanh_f(c);
      ccur[(size_t)row*512 + j] = c;
      hcur[(size_t)row*512 + j] = (bf16)h;
    }
  }
}

// ---- level BM=64 (exact R7 body, Uall-packed): for small levels ----
__global__ __launch_bounds__(256)
void level_kernel(const bf16* __restrict__ hprev, bf16* __restrict__ hcur,
                  const float* __restrict__ cprev, float* __restrict__ ccur,
                  const bf16* __restrict__ Uall, const float* __restrict__ Uioub,
                  const float* __restrict__ Ufb)
{
  __shared__ bf16 lsA[64*40];
  __shared__ bf16 lsB[5][64*40];
  const int t = threadIdx.x;
  const int mrow0 = blockIdx.x*64, nblk = blockIdx.y*64;
  const int r = t>>2, kc = (t&3)*8;
  const int lane16 = t&15, quad = (t&63)>>4, w = t>>6;

  f32x4 acc[5][4];
  const f32x4 zero = {0.f,0.f,0.f,0.f};
  #pragma unroll
  for(int o=0;o<5;o++){
    #pragma unroll
    for(int rt=0;rt<4;rt++) acc[o][rt]=zero;
  }

  const bf16* arow = hprev + (size_t)(mrow0 + r)*1024;   // children rows contiguous
  const int col = nblk + r;
  for (int k0=0;k0<1024;k0+=32){
    *(bf16x8*)&lsA[r*40+kc]    = *(const bf16x8*)&arow[k0+kc];
    #pragma unroll
    for(int g=0;g<5;g++)
      *(bf16x8*)&lsB[g][r*40+kc] = *(const bf16x8*)&Uall[(size_t)(g*512+col)*1024 + k0+kc];
    __syncthreads();
    bf16x8 bfrag[5];
    #pragma unroll
    for(int o=0;o<5;o++) bfrag[o] = *(const bf16x8*)&lsB[o][(w*16+lane16)*40 + quad*8];
    #pragma unroll
    for(int rt=0;rt<4;rt++){
      bf16x8 a = *(const bf16x8*)&lsA[(rt*16+lane16)*40 + quad*8];
      #pragma unroll
      for(int o=0;o<5;o++)
        acc[o][rt] = __builtin_amdgcn_mfma_f32_16x16x32_bf16(a, bfrag[o], acc[o][rt], 0,0,0);
    }
    __syncthreads();
  }
  const int j = nblk + w*16 + lane16;
  const float bi =Uioub[j], bo=Uioub[512+j], bu=Uioub[1024+j];
  const float bfl=Ufb[j],   bfr=Ufb[512+j];
  #pragma unroll
  for(int rt=0;rt<4;rt++){
    #pragma unroll
    for(int reg=0;reg<4;reg++){
      const int row = mrow0 + rt*16 + quad*4 + reg;
      float iv=acc[0][rt][reg]+bi, ov=acc[1][rt][reg]+bo, uv=acc[2][rt][reg]+bu;
      float fl=acc[3][rt][reg]+bfl, fr=acc[4][rt][reg]+bfr;
      float cl = cprev[((size_t)row*2  )*512 + j];
      float cr = cprev[((size_t)row*2+1)*512 + j];
      float cf = sigm(fl)*cl + sigm(fr)*cr;
      float c  = sigm(iv)*tanh_f(uv) + cf;
      float h  = sigm(ov)*tanh_f(c);
      ccur[(size_t)row*512 + j] = c;
      hcur[(size_t)row*512 + j] = (bf16)h;
    }
  }
}

// ---- level BM=128 (R7 staging/addressing, 8 row-tiles/wave): for big levels ----
__global__ __launch_bounds__(256, 2)
void level128_kernel(const bf16* __restrict__ hprev, bf16* __restrict__ hcur,
                     const float* __restrict__ cprev, float* __restrict__ ccur,
                     const bf16* __restrict__ Uall, const float* __restrict__ Uioub,
                     const float* __restrict__ Ufb)
{
  __shared__ bf16 lsA[128*40];     // 10 KB, two 64-row stride-40 tiles stacked
  __shared__ bf16 lsB[5][64*40];   // 25 KB
  const int t = threadIdx.x;
  const int mrow0 = blockIdx.x*128, nblk = blockIdx.y*64;
  const int r = t>>2, kc = (t&3)*8;
  const int lane16 = t&15, quad = (t&63)>>4, w = t>>6;

  f32x4 acc[5][8];
  const f32x4 zero = {0.f,0.f,0.f,0.f};
  #pragma unroll
  for(int o=0;o<5;o++){
    #pragma unroll
    for(int rt=0;rt<8;rt++) acc[o][rt]=zero;
  }

  const bf16* arow0 = hprev + (size_t)(mrow0 + r)*1024;
  const bf16* arow1 = hprev + (size_t)(mrow0 + 64 + r)*1024;
  const int col = nblk + r;
  for (int k0=0;k0<1024;k0+=32){
    *(bf16x8*)&lsA[r*40+kc]        = *(const bf16x8*)&arow0[k0+kc];
    *(bf16x8*)&lsA[(64+r)*40+kc]   = *(const bf16x8*)&arow1[k0+kc];
    #pragma unroll
    for(int g=0;g<5;g++)
      *(bf16x8*)&lsB[g][r*40+kc] = *(const bf16x8*)&Uall[(size_t)(g*512+col)*1024 + k0+kc];
    __syncthreads();
    bf16x8 bfrag[5];
    #pragma unroll
    for(int g=0;g<5;g++) bfrag[g] = *(const bf16x8*)&lsB[g][(w*16+lane16)*40 + quad*8];
    #pragma unroll
    for(int rt=0;rt<8;rt++){
      bf16x8 a = *(const bf16x8*)&lsA[(rt*16+lane16)*40 + quad*8];
      #pragma unroll
      for(int g=0;g<5;g++)
        acc[g][rt] = __builtin_amdgcn_mfma_f32_16x16x32_bf16(a, bfrag[g], acc[g][rt], 0,0,0);
    }
    __syncthreads();
  }
  const int j = nblk + w*16 + lane16;
  const float bi =Uioub[j], bo=Uioub[512+j], bu=Uioub[1024+j];
  const float bfl=Ufb[j],   bfr=Ufb[512+j];
  #pragma unroll
  for(int rt=0;rt<8;rt++){
    #pragma unroll
    for(int reg=0;reg<4;reg++){
      const int row = mrow0 + rt*16 + quad*4 + reg;
      float iv=acc[0][rt][reg]+bi, ov=acc[1][rt][reg]+bo, uv=acc[2][rt][reg]+bu;
      float fl=acc[3][rt][reg]+bfl, fr=acc[4][rt][reg]+bfr;
      float cl = cprev[((size_t)row*2  )*512 + j];
      float cr = cprev[((size_t)row*2+1)*512 + j];
      float cf = sigm(fl)*cl + sigm(fr)*cr;
      float c  = sigm(iv)*tanh_f(uv) + cf;
      float h  = sigm(ov)*tanh_f(c);
      ccur[(size_t)row*512 + j] = c;
      hcur[(size_t)row*512 + j] = (bf16)h;
    }
  }
}

// ---- logits: out[node*5+c] = h_row . lin_w[c] + lin_b[c] ----
__global__ __launch_bounds__(256)
void logits_kernel(const bf16* __restrict__ h, const float* __restrict__ linw,
                   const float* __restrict__ linb, float* __restrict__ out,
                   int rowbase, int lgm, int mask, int off){
  const int row = blockIdx.x*4 + (threadIdx.x>>6);
  const int l = threadIdx.x & 63;
  bf16x8 hv = *(const bf16x8*)(h + (size_t)row*512 + l*8);
  float hf[8];
  #pragma unroll
  for(int jj=0;jj<8;jj++) hf[jj] = (float)hv[jj];
  float s[5];
  #pragma unroll
  for(int c=0;c<5;c++){
    const f32x4 w0 = *(const f32x4*)(linw + c*512 + l*8);
    const f32x4 w1 = *(const f32x4*)(linw + c*512 + l*8 + 4);
    float a = 0.f;
    #pragma unroll
    for(int jj=0;jj<4;jj++) a += hf[jj]*w0[jj] + hf[4+jj]*w1[jj];
    s[c]=a;
  }
  #pragma unroll
  for(int o=32;o>0;o>>=1){
    #pragma unroll
    for(int c=0;c<5;c++) s[c] += __shfl_down(s[c], o, 64);
  }
  if (l==0){
    const int g = rowbase + row;
    const int node = (g>>lgm)*511 + off + (g&mask);
    #pragma unroll
    for(int c=0;c<5;c++) out[(size_t)node*5+c] = s[c] + linb[c];
  }
}

__global__ void zero_out(float* out, int n){
  int i = blockIdx.x*256 + threadIdx.x;
  if (i < n) out[i] = 0.f;
}

extern "C" void kernel_launch(void* const* d_in, const int* in_sizes, int n_in,
                              void* d_out, int out_size, void* d_ws, size_t ws_size,
                              hipStream_t stream)
{
  const int*   wordid = (const int*)d_in[0];
  const float* emb    = (const float*)d_in[1];
  const float* Wiou   = (const float*)d_in[2];
  const float* Wioub  = (const float*)d_in[3];
  const float* Uiou   = (const float*)d_in[4];
  const float* Uioub  = (const float*)d_in[5];
  const float* Uf     = (const float*)d_in[6];
  const float* Ufb    = (const float*)d_in[7];
  const float* linw   = (const float*)d_in[8];
  const float* linb   = (const float*)d_in[9];
  float* out = (float*)d_out;

  // ---- fixed-region layout (R7) ----
  const size_t oWPD  = 0;
  const size_t oUALL = oWPD  + (size_t)1536*320*2;
  const size_t oEMB  = oUALL + (size_t)2560*1024*2;
  const size_t oH1   = oEMB  + (size_t)32000*320*2;
  const size_t oC1   = oH1   + (size_t)32768*512*2;
  const size_t oH0   = oC1   + (size_t)32768*512*4;
  size_t R0 = 0;
  {
    const size_t t4 = oH0 + (size_t)16384*512*(2+4);   // 177.7 MB
    const size_t t8 = oH0 + (size_t) 8192*512*(2+4);   // 152.5 MB
    if      (ws_size >= t4) R0 = 16384;
    else if (ws_size >= t8) R0 = 8192;
  }
  if (R0 == 0){
    zero_out<<<(out_size+255)/256, 256, 0, stream>>>(out, out_size);
    return;
  }

  char* ws = (char*)d_ws;
  bf16*  Wpad = (bf16*)(ws + oWPD);
  bf16*  Uall = (bf16*)(ws + oUALL);
  bf16*  embp = (bf16*)(ws + oEMB);
  bf16*  h1   = (bf16*)(ws + oH1);
  float* c1   = (float*)(ws + oC1);
  bf16*  h0   = (bf16*)(ws + oH0);
  float* c0   = (float*)(ws + oH0 + R0*1024);

  cvt_pad_w<<<1536, 320, 0, stream>>>(Wiou, Wpad);
  cvt_u<<<(2560*1024+255)/256, 256, 0, stream>>>(Uiou, Uf, Uall);
  cvt_emb<<<32000, 320, 0, stream>>>(emb, embp);

  const int offs[9] = {0,256,384,448,480,496,504,508,510};
  const int nchunk = (int)(65536 / R0);

  // ---- leaf + level-1, chunked through h0/c0 scratch ----
  for (int ch = 0; ch < nchunk; ch++){
    const int* wid = wordid + (size_t)ch*R0;
    leaf_kernel<<<dim3((int)(R0/64), 8), 256, 0, stream>>>(wid, embp, Wpad, Wioub, h0, c0);
    logits_kernel<<<(int)(R0/4), 256, 0, stream>>>(h0, linw, linb, out,
                                                   (int)(ch*R0), 8, 255, 0);
    bf16*  h1c = h1 + (size_t)ch*(R0/2)*512;
    float* c1c = c1 + (size_t)ch*(R0/2)*512;
    const int orows = (int)(R0/2);                 // out rows this chunk (>=4096)
    level128_kernel<<<dim3(orows/128, 8), 256, 0, stream>>>(h0, h1c, c0, c1c,
                                                            Uall, Uioub, Ufb);
  }
  logits_kernel<<<32768/4, 256, 0, stream>>>(h1, linw, linb, out, 0, 7, 127, offs[1]);

  // ---- levels 2..8: ping-pong h1/c1 <-> h0/c0 regions ----
  for (int lv = 2; lv <= 8; lv++){
    const int rows = 65536 >> lv;
    const bf16*  hin  = (lv & 1) ? h0 : h1;
    bf16*        hout = (lv & 1) ? h1 : h0;
    const float* cin  = (lv & 1) ? c0 : c1;
    float*       cout = (lv & 1) ? c1 : c0;
    if (rows >= 4096)
      level128_kernel<<<dim3(rows/128, 8), 256, 0, stream>>>(hin, hout, cin, cout,
                                                             Uall, Uioub, Ufb);
    else
      level_kernel<<<dim3(rows/64, 8), 256, 0, stream>>>(hin, hout, cin, cout,
                                                         Uall, Uioub, Ufb);
    logits_kernel<<<rows/4, 256, 0, stream>>>(hout, linw, linb, out,
                                              0, 8-lv, (256>>lv)-1, offs[lv]);
  }
}

// Round 12
// 901.759 us; speedup vs baseline: 1.7615x; 1.0204x over previous
//
#include <hip/hip_runtime.h>
#include <hip/hip_bf16.h>

// TreeLSTM on MI355X. B=256 trees, 256 leaves (depth 9), H=512, C=5.
// f32 I/O; bf16 MFMA; f32 cell state. Output f32 [256,511,5].
//
// R12 = R11 (920us) + BM=128 leaf kernel (same R7-proven staging: stride-40 LDS,
// loads-at-top K-loop; acc[3][8]). level128 for levels>=4096 rows; BM=64 for tail.
// Launcher/memory plan identical to R7/R11.

typedef __bf16 bf16;
typedef bf16  bf16x8 __attribute__((ext_vector_type(8)));
typedef float f32x4  __attribute__((ext_vector_type(4)));

__device__ __forceinline__ float sigm(float x){ return 1.0f/(1.0f + __expf(-x)); }
__device__ __forceinline__ float tanh_f(float x){ return 1.0f - 2.0f/(__expf(2.0f*x)+1.0f); }

// ---- converts ----
__global__ void cvt_pad_w(const float* __restrict__ src, bf16* __restrict__ dst){
  const int row = blockIdx.x, c = threadIdx.x;   // 1536 x 320
  dst[row*320 + c] = (bf16)(c < 300 ? src[row*300 + c] : 0.f);
}
__global__ void cvt_emb(const float* __restrict__ src, bf16* __restrict__ dst){
  const int row = blockIdx.x, c = threadIdx.x;   // 32000 x 320
  dst[row*320 + c] = (bf16)(c < 300 ? src[(size_t)row*300 + c] : 0.f);
}
// pack U: rows 0..1535 = U_iou, rows 1536..2559 = U_f -> Uall[2560][1024] bf16
__global__ void cvt_u(const float* __restrict__ Uiou, const float* __restrict__ Uf,
                      bf16* __restrict__ dst){
  const int i = blockIdx.x*256 + threadIdx.x;
  if (i < 2560*1024)
    dst[i] = (bf16)(i < 1536*1024 ? Uiou[i] : Uf[i - 1536*1024]);
}

// ---- leaf BM=128: x=embp[wordid]; iou = x @ W_iou^T + b; cell ----
__global__ __launch_bounds__(256, 2)
void leaf128_kernel(const int* __restrict__ wordid, const bf16* __restrict__ embp,
                    const bf16* __restrict__ Wpad, const float* __restrict__ Wb,
                    bf16* __restrict__ hcur, float* __restrict__ ccur)
{
  __shared__ bf16 lsA[128*40];     // 10 KB, two 64-row stride-40 tiles stacked
  __shared__ bf16 lsB[3][64*40];   // 15 KB
  const int t = threadIdx.x;
  const int mrow0 = blockIdx.x*128, nblk = blockIdx.y*64;
  const int r = t>>2, kc = (t&3)*8;
  const int lane16 = t&15, quad = (t&63)>>4, w = t>>6;

  f32x4 acc[3][8];
  const f32x4 zero = {0.f,0.f,0.f,0.f};
  #pragma unroll
  for(int o=0;o<3;o++){
    #pragma unroll
    for(int rt=0;rt<8;rt++) acc[o][rt]=zero;
  }

  const int wid0 = wordid[mrow0 + r];
  const int wid1 = wordid[mrow0 + 64 + r];
  const bf16* arow0 = embp + (size_t)wid0*320;
  const bf16* arow1 = embp + (size_t)wid1*320;
  const int col = nblk + r;
  for (int k0=0;k0<320;k0+=32){
    *(bf16x8*)&lsA[r*40+kc]      = *(const bf16x8*)&arow0[k0+kc];
    *(bf16x8*)&lsA[(64+r)*40+kc] = *(const bf16x8*)&arow1[k0+kc];
    #pragma unroll
    for(int g=0;g<3;g++)
      *(bf16x8*)&lsB[g][r*40+kc] = *(const bf16x8*)&Wpad[(size_t)(g*512+col)*320 + k0+kc];
    __syncthreads();
    bf16x8 bfrag[3];
    #pragma unroll
    for(int g=0;g<3;g++) bfrag[g] = *(const bf16x8*)&lsB[g][(w*16+lane16)*40 + quad*8];
    #pragma unroll
    for(int rt=0;rt<8;rt++){
      bf16x8 a = *(const bf16x8*)&lsA[(rt*16+lane16)*40 + quad*8];
      #pragma unroll
      for(int g=0;g<3;g++)
        acc[g][rt] = __builtin_amdgcn_mfma_f32_16x16x32_bf16(a, bfrag[g], acc[g][rt], 0,0,0);
    }
    __syncthreads();
  }
  const int j = nblk + w*16 + lane16;
  const float bi=Wb[j], bo=Wb[512+j], bu=Wb[1024+j];
  #pragma unroll
  for(int rt=0;rt<8;rt++){
    #pragma unroll
    for(int reg=0;reg<4;reg++){
      const int row = mrow0 + rt*16 + quad*4 + reg;   // C/D: row=quad*4+reg, col=lane16
      float iv=acc[0][rt][reg]+bi, ov=acc[1][rt][reg]+bo, uv=acc[2][rt][reg]+bu;
      float c = sigm(iv)*tanh_f(uv);
      float h = sigm(ov)*tanh_f(c);
      ccur[(size_t)row*512 + j] = c;
      hcur[(size_t)row*512 + j] = (bf16)h;
    }
  }
}

// ---- level BM=64 (R7 body, Uall-packed): small levels ----
__global__ __launch_bounds__(256)
void level_kernel(const bf16* __restrict__ hprev, bf16* __restrict__ hcur,
                  const float* __restrict__ cprev, float* __restrict__ ccur,
                  const bf16* __restrict__ Uall, const float* __restrict__ Uioub,
                  const float* __restrict__ Ufb)
{
  __shared__ bf16 lsA[64*40];
  __shared__ bf16 lsB[5][64*40];
  const int t = threadIdx.x;
  const int mrow0 = blockIdx.x*64, nblk = blockIdx.y*64;
  const int r = t>>2, kc = (t&3)*8;
  const int lane16 = t&15, quad = (t&63)>>4, w = t>>6;

  f32x4 acc[5][4];
  const f32x4 zero = {0.f,0.f,0.f,0.f};
  #pragma unroll
  for(int o=0;o<5;o++){
    #pragma unroll
    for(int rt=0;rt<4;rt++) acc[o][rt]=zero;
  }

  const bf16* arow = hprev + (size_t)(mrow0 + r)*1024;   // children rows contiguous
  const int col = nblk + r;
  for (int k0=0;k0<1024;k0+=32){
    *(bf16x8*)&lsA[r*40+kc] = *(const bf16x8*)&arow[k0+kc];
    #pragma unroll
    for(int g=0;g<5;g++)
      *(bf16x8*)&lsB[g][r*40+kc] = *(const bf16x8*)&Uall[(size_t)(g*512+col)*1024 + k0+kc];
    __syncthreads();
    bf16x8 bfrag[5];
    #pragma unroll
    for(int o=0;o<5;o++) bfrag[o] = *(const bf16x8*)&lsB[o][(w*16+lane16)*40 + quad*8];
    #pragma unroll
    for(int rt=0;rt<4;rt++){
      bf16x8 a = *(const bf16x8*)&lsA[(rt*16+lane16)*40 + quad*8];
      #pragma unroll
      for(int o=0;o<5;o++)
        acc[o][rt] = __builtin_amdgcn_mfma_f32_16x16x32_bf16(a, bfrag[o], acc[o][rt], 0,0,0);
    }
    __syncthreads();
  }
  const int j = nblk + w*16 + lane16;
  const float bi =Uioub[j], bo=Uioub[512+j], bu=Uioub[1024+j];
  const float bfl=Ufb[j],   bfr=Ufb[512+j];
  #pragma unroll
  for(int rt=0;rt<4;rt++){
    #pragma unroll
    for(int reg=0;reg<4;reg++){
      const int row = mrow0 + rt*16 + quad*4 + reg;
      float iv=acc[0][rt][reg]+bi, ov=acc[1][rt][reg]+bo, uv=acc[2][rt][reg]+bu;
      float fl=acc[3][rt][reg]+bfl, fr=acc[4][rt][reg]+bfr;
      float cl = cprev[((size_t)row*2  )*512 + j];
      float cr = cprev[((size_t)row*2+1)*512 + j];
      float cf = sigm(fl)*cl + sigm(fr)*cr;
      float c  = sigm(iv)*tanh_f(uv) + cf;
      float h  = sigm(ov)*tanh_f(c);
      ccur[(size_t)row*512 + j] = c;
      hcur[(size_t)row*512 + j] = (bf16)h;
    }
  }
}

// ---- level BM=128 (R11, proven 122us): big levels ----
__global__ __launch_bounds__(256, 2)
void level128_kernel(const bf16* __restrict__ hprev, bf16* __restrict__ hcur,
                     const float* __restrict__ cprev, float* __restrict__ ccur,
                     const bf16* __restrict__ Uall, const float* __restrict__ Uioub,
                     const float* __restrict__ Ufb)
{
  __shared__ bf16 lsA[128*40];
  __shared__ bf16 lsB[5][64*40];
  const int t = threadIdx.x;
  const int mrow0 = blockIdx.x*128, nblk = blockIdx.y*64;
  const int r = t>>2, kc = (t&3)*8;
  const int lane16 = t&15, quad = (t&63)>>4, w = t>>6;

  f32x4 acc[5][8];
  const f32x4 zero = {0.f,0.f,0.f,0.f};
  #pragma unroll
  for(int o=0;o<5;o++){
    #pragma unroll
    for(int rt=0;rt<8;rt++) acc[o][rt]=zero;
  }

  const bf16* arow0 = hprev + (size_t)(mrow0 + r)*1024;
  const bf16* arow1 = hprev + (size_t)(mrow0 + 64 + r)*1024;
  const int col = nblk + r;
  for (int k0=0;k0<1024;k0+=32){
    *(bf16x8*)&lsA[r*40+kc]      = *(const bf16x8*)&arow0[k0+kc];
    *(bf16x8*)&lsA[(64+r)*40+kc] = *(const bf16x8*)&arow1[k0+kc];
    #pragma unroll
    for(int g=0;g<5;g++)
      *(bf16x8*)&lsB[g][r*40+kc] = *(const bf16x8*)&Uall[(size_t)(g*512+col)*1024 + k0+kc];
    __syncthreads();
    bf16x8 bfrag[5];
    #pragma unroll
    for(int g=0;g<5;g++) bfrag[g] = *(const bf16x8*)&lsB[g][(w*16+lane16)*40 + quad*8];
    #pragma unroll
    for(int rt=0;rt<8;rt++){
      bf16x8 a = *(const bf16x8*)&lsA[(rt*16+lane16)*40 + quad*8];
      #pragma unroll
      for(int g=0;g<5;g++)
        acc[g][rt] = __builtin_amdgcn_mfma_f32_16x16x32_bf16(a, bfrag[g], acc[g][rt], 0,0,0);
    }
    __syncthreads();
  }
  const int j = nblk + w*16 + lane16;
  const float bi =Uioub[j], bo=Uioub[512+j], bu=Uioub[1024+j];
  const float bfl=Ufb[j],   bfr=Ufb[512+j];
  #pragma unroll
  for(int rt=0;rt<8;rt++){
    #pragma unroll
    for(int reg=0;reg<4;reg++){
      const int row = mrow0 + rt*16 + quad*4 + reg;
      float iv=acc[0][rt][reg]+bi, ov=acc[1][rt][reg]+bo, uv=acc[2][rt][reg]+bu;
      float fl=acc[3][rt][reg]+bfl, fr=acc[4][rt][reg]+bfr;
      float cl = cprev[((size_t)row*2  )*512 + j];
      float cr = cprev[((size_t)row*2+1)*512 + j];
      float cf = sigm(fl)*cl + sigm(fr)*cr;
      float c  = sigm(iv)*tanh_f(uv) + cf;
      float h  = sigm(ov)*tanh_f(c);
      ccur[(size_t)row*512 + j] = c;
      hcur[(size_t)row*512 + j] = (bf16)h;
    }
  }
}

// ---- logits: out[node*5+c] = h_row . lin_w[c] + lin_b[c] ----
__global__ __launch_bounds__(256)
void logits_kernel(const bf16* __restrict__ h, const float* __restrict__ linw,
                   const float* __restrict__ linb, float* __restrict__ out,
                   int rowbase, int lgm, int mask, int off){
  const int row = blockIdx.x*4 + (threadIdx.x>>6);
  const int l = threadIdx.x & 63;
  bf16x8 hv = *(const bf16x8*)(h + (size_t)row*512 + l*8);
  float hf[8];
  #pragma unroll
  for(int jj=0;jj<8;jj++) hf[jj] = (float)hv[jj];
  float s[5];
  #pragma unroll
  for(int c=0;c<5;c++){
    const f32x4 w0 = *(const f32x4*)(linw + c*512 + l*8);
    const f32x4 w1 = *(const f32x4*)(linw + c*512 + l*8 + 4);
    float a = 0.f;
    #pragma unroll
    for(int jj=0;jj<4;jj++) a += hf[jj]*w0[jj] + hf[4+jj]*w1[jj];
    s[c]=a;
  }
  #pragma unroll
  for(int o=32;o>0;o>>=1){
    #pragma unroll
    for(int c=0;c<5;c++) s[c] += __shfl_down(s[c], o, 64);
  }
  if (l==0){
    const int g = rowbase + row;
    const int node = (g>>lgm)*511 + off + (g&mask);
    #pragma unroll
    for(int c=0;c<5;c++) out[(size_t)node*5+c] = s[c] + linb[c];
  }
}

__global__ void zero_out(float* out, int n){
  int i = blockIdx.x*256 + threadIdx.x;
  if (i < n) out[i] = 0.f;
}

extern "C" void kernel_launch(void* const* d_in, const int* in_sizes, int n_in,
                              void* d_out, int out_size, void* d_ws, size_t ws_size,
                              hipStream_t stream)
{
  const int*   wordid = (const int*)d_in[0];
  const float* emb    = (const float*)d_in[1];
  const float* Wiou   = (const float*)d_in[2];
  const float* Wioub  = (const float*)d_in[3];
  const float* Uiou   = (const float*)d_in[4];
  const float* Uioub  = (const float*)d_in[5];
  const float* Uf     = (const float*)d_in[6];
  const float* Ufb    = (const float*)d_in[7];
  const float* linw   = (const float*)d_in[8];
  const float* linb   = (const float*)d_in[9];
  float* out = (float*)d_out;

  // ---- fixed-region layout (R7) ----
  const size_t oWPD  = 0;
  const size_t oUALL = oWPD  + (size_t)1536*320*2;
  const size_t oEMB  = oUALL + (size_t)2560*1024*2;
  const size_t oH1   = oEMB  + (size_t)32000*320*2;
  const size_t oC1   = oH1   + (size_t)32768*512*2;
  const size_t oH0   = oC1   + (size_t)32768*512*4;
  size_t R0 = 0;
  {
    const size_t t4 = oH0 + (size_t)16384*512*(2+4);   // 177.7 MB
    const size_t t8 = oH0 + (size_t) 8192*512*(2+4);   // 152.5 MB
    if      (ws_size >= t4) R0 = 16384;
    else if (ws_size >= t8) R0 = 8192;
  }
  if (R0 == 0){
    zero_out<<<(out_size+255)/256, 256, 0, stream>>>(out, out_size);
    return;
  }

  char* ws = (char*)d_ws;
  bf16*  Wpad = (bf16*)(ws + oWPD);
  bf16*  Uall = (bf16*)(ws + oUALL);
  bf16*  embp = (bf16*)(ws + oEMB);
  bf16*  h1   = (bf16*)(ws + oH1);
  float* c1   = (float*)(ws + oC1);
  bf16*  h0   = (bf16*)(ws + oH0);
  float* c0   = (float*)(ws + oH0 + R0*1024);

  cvt_pad_w<<<1536, 320, 0, stream>>>(Wiou, Wpad);
  cvt_u<<<(2560*1024+255)/256, 256, 0, stream>>>(Uiou, Uf, Uall);
  cvt_emb<<<32000, 320, 0, stream>>>(emb, embp);

  const int offs[9] = {0,256,384,448,480,496,504,508,510};
  const int nchunk = (int)(65536 / R0);

  // ---- leaf + level-1, chunked through h0/c0 scratch ----
  for (int ch = 0; ch < nchunk; ch++){
    const int* wid = wordid + (size_t)ch*R0;
    leaf128_kernel<<<dim3((int)(R0/128), 8), 256, 0, stream>>>(wid, embp, Wpad, Wioub,
                                                               h0, c0);
    logits_kernel<<<(int)(R0/4), 256, 0, stream>>>(h0, linw, linb, out,
                                                   (int)(ch*R0), 8, 255, 0);
    bf16*  h1c = h1 + (size_t)ch*(R0/2)*512;
    float* c1c = c1 + (size_t)ch*(R0/2)*512;
    const int orows = (int)(R0/2);
    level128_kernel<<<dim3(orows/128, 8), 256, 0, stream>>>(h0, h1c, c0, c1c,
                                                            Uall, Uioub, Ufb);
  }
  logits_kernel<<<32768/4, 256, 0, stream>>>(h1, linw, linb, out, 0, 7, 127, offs[1]);

  // ---- levels 2..8: ping-pong h1/c1 <-> h0/c0 regions ----
  for (int lv = 2; lv <= 8; lv++){
    const int rows = 65536 >> lv;
    const bf16*  hin  = (lv & 1) ? h0 : h1;
    bf16*        hout = (lv & 1) ? h1 : h0;
    const float* cin  = (lv & 1) ? c0 : c1;
    float*       cout = (lv & 1) ? c1 : c0;
    if (rows >= 4096)
      level128_kernel<<<dim3(rows/128, 8), 256, 0, stream>>>(hin, hout, cin, cout,
                                                             Uall, Uioub, Ufb);
    else
      level_kernel<<<dim3(rows/64, 8), 256, 0, stream>>>(hin, hout, cin, cout,
                                                         Uall, Uioub, Ufb);
    logits_kernel<<<rows/4, 256, 0, stream>>>(hout, linw, linb, out,
                                              0, 8-lv, (256>>lv)-1, offs[lv]);
  }
}

// Round 14
// 871.127 us; speedup vs baseline: 1.8234x; 1.0352x over previous
//
#include <hip/hip_runtime.h>
#include <hip/hip_bf16.h>

// TreeLSTM on MI355X. B=256 trees, 256 leaves (depth 9), H=512, C=5.
// f32 I/O; bf16 MFMA; f32 cell state. Output f32 [256,511,5].
//
// R14 = R12 (902us, proven) + R0=32768 ws tier (2 chunks instead of 4 when
// ws >= 228 MB). Fused-logits experiment (R13) reverted — failed correctness.

typedef __bf16 bf16;
typedef bf16  bf16x8 __attribute__((ext_vector_type(8)));
typedef float f32x4  __attribute__((ext_vector_type(4)));

__device__ __forceinline__ float sigm(float x){ return 1.0f/(1.0f + __expf(-x)); }
__device__ __forceinline__ float tanh_f(float x){ return 1.0f - 2.0f/(__expf(2.0f*x)+1.0f); }

// ---- converts ----
__global__ void cvt_pad_w(const float* __restrict__ src, bf16* __restrict__ dst){
  const int row = blockIdx.x, c = threadIdx.x;   // 1536 x 320
  dst[row*320 + c] = (bf16)(c < 300 ? src[row*300 + c] : 0.f);
}
__global__ void cvt_emb(const float* __restrict__ src, bf16* __restrict__ dst){
  const int row = blockIdx.x, c = threadIdx.x;   // 32000 x 320
  dst[row*320 + c] = (bf16)(c < 300 ? src[(size_t)row*300 + c] : 0.f);
}
__global__ void cvt_u(const float* __restrict__ Uiou, const float* __restrict__ Uf,
                      bf16* __restrict__ dst){
  const int i = blockIdx.x*256 + threadIdx.x;
  if (i < 2560*1024)
    dst[i] = (bf16)(i < 1536*1024 ? Uiou[i] : Uf[i - 1536*1024]);
}

// ---- leaf BM=128: x=embp[wordid]; iou = x @ W_iou^T + b; cell ----
__global__ __launch_bounds__(256, 2)
void leaf128_kernel(const int* __restrict__ wordid, const bf16* __restrict__ embp,
                    const bf16* __restrict__ Wpad, const float* __restrict__ Wb,
                    bf16* __restrict__ hcur, float* __restrict__ ccur)
{
  __shared__ bf16 lsA[128*40];
  __shared__ bf16 lsB[3][64*40];
  const int t = threadIdx.x;
  const int mrow0 = blockIdx.x*128, nblk = blockIdx.y*64;
  const int r = t>>2, kc = (t&3)*8;
  const int lane16 = t&15, quad = (t&63)>>4, w = t>>6;

  f32x4 acc[3][8];
  const f32x4 zero = {0.f,0.f,0.f,0.f};
  #pragma unroll
  for(int o=0;o<3;o++){
    #pragma unroll
    for(int rt=0;rt<8;rt++) acc[o][rt]=zero;
  }

  const int wid0 = wordid[mrow0 + r];
  const int wid1 = wordid[mrow0 + 64 + r];
  const bf16* arow0 = embp + (size_t)wid0*320;
  const bf16* arow1 = embp + (size_t)wid1*320;
  const int col = nblk + r;
  for (int k0=0;k0<320;k0+=32){
    *(bf16x8*)&lsA[r*40+kc]      = *(const bf16x8*)&arow0[k0+kc];
    *(bf16x8*)&lsA[(64+r)*40+kc] = *(const bf16x8*)&arow1[k0+kc];
    #pragma unroll
    for(int g=0;g<3;g++)
      *(bf16x8*)&lsB[g][r*40+kc] = *(const bf16x8*)&Wpad[(size_t)(g*512+col)*320 + k0+kc];
    __syncthreads();
    bf16x8 bfrag[3];
    #pragma unroll
    for(int g=0;g<3;g++) bfrag[g] = *(const bf16x8*)&lsB[g][(w*16+lane16)*40 + quad*8];
    #pragma unroll
    for(int rt=0;rt<8;rt++){
      bf16x8 a = *(const bf16x8*)&lsA[(rt*16+lane16)*40 + quad*8];
      #pragma unroll
      for(int g=0;g<3;g++)
        acc[g][rt] = __builtin_amdgcn_mfma_f32_16x16x32_bf16(a, bfrag[g], acc[g][rt], 0,0,0);
    }
    __syncthreads();
  }
  const int j = nblk + w*16 + lane16;
  const float bi=Wb[j], bo=Wb[512+j], bu=Wb[1024+j];
  #pragma unroll
  for(int rt=0;rt<8;rt++){
    #pragma unroll
    for(int reg=0;reg<4;reg++){
      const int row = mrow0 + rt*16 + quad*4 + reg;   // C/D: row=quad*4+reg, col=lane16
      float iv=acc[0][rt][reg]+bi, ov=acc[1][rt][reg]+bo, uv=acc[2][rt][reg]+bu;
      float c = sigm(iv)*tanh_f(uv);
      float h = sigm(ov)*tanh_f(c);
      ccur[(size_t)row*512 + j] = c;
      hcur[(size_t)row*512 + j] = (bf16)h;
    }
  }
}

// ---- level BM=64 (R7 body, Uall-packed): small levels ----
__global__ __launch_bounds__(256)
void level_kernel(const bf16* __restrict__ hprev, bf16* __restrict__ hcur,
                  const float* __restrict__ cprev, float* __restrict__ ccur,
                  const bf16* __restrict__ Uall, const float* __restrict__ Uioub,
                  const float* __restrict__ Ufb)
{
  __shared__ bf16 lsA[64*40];
  __shared__ bf16 lsB[5][64*40];
  const int t = threadIdx.x;
  const int mrow0 = blockIdx.x*64, nblk = blockIdx.y*64;
  const int r = t>>2, kc = (t&3)*8;
  const int lane16 = t&15, quad = (t&63)>>4, w = t>>6;

  f32x4 acc[5][4];
  const f32x4 zero = {0.f,0.f,0.f,0.f};
  #pragma unroll
  for(int o=0;o<5;o++){
    #pragma unroll
    for(int rt=0;rt<4;rt++) acc[o][rt]=zero;
  }

  const bf16* arow = hprev + (size_t)(mrow0 + r)*1024;   // children rows contiguous
  const int col = nblk + r;
  for (int k0=0;k0<1024;k0+=32){
    *(bf16x8*)&lsA[r*40+kc] = *(const bf16x8*)&arow[k0+kc];
    #pragma unroll
    for(int g=0;g<5;g++)
      *(bf16x8*)&lsB[g][r*40+kc] = *(const bf16x8*)&Uall[(size_t)(g*512+col)*1024 + k0+kc];
    __syncthreads();
    bf16x8 bfrag[5];
    #pragma unroll
    for(int o=0;o<5;o++) bfrag[o] = *(const bf16x8*)&lsB[o][(w*16+lane16)*40 + quad*8];
    #pragma unroll
    for(int rt=0;rt<4;rt++){
      bf16x8 a = *(const bf16x8*)&lsA[(rt*16+lane16)*40 + quad*8];
      #pragma unroll
      for(int o=0;o<5;o++)
        acc[o][rt] = __builtin_amdgcn_mfma_f32_16x16x32_bf16(a, bfrag[o], acc[o][rt], 0,0,0);
    }
    __syncthreads();
  }
  const int j = nblk + w*16 + lane16;
  const float bi =Uioub[j], bo=Uioub[512+j], bu=Uioub[1024+j];
  const float bfl=Ufb[j],   bfr=Ufb[512+j];
  #pragma unroll
  for(int rt=0;rt<4;rt++){
    #pragma unroll
    for(int reg=0;reg<4;reg++){
      const int row = mrow0 + rt*16 + quad*4 + reg;
      float iv=acc[0][rt][reg]+bi, ov=acc[1][rt][reg]+bo, uv=acc[2][rt][reg]+bu;
      float fl=acc[3][rt][reg]+bfl, fr=acc[4][rt][reg]+bfr;
      float cl = cprev[((size_t)row*2  )*512 + j];
      float cr = cprev[((size_t)row*2+1)*512 + j];
      float cf = sigm(fl)*cl + sigm(fr)*cr;
      float c  = sigm(iv)*tanh_f(uv) + cf;
      float h  = sigm(ov)*tanh_f(c);
      ccur[(size_t)row*512 + j] = c;
      hcur[(size_t)row*512 + j] = (bf16)h;
    }
  }
}

// ---- level BM=128 (R11, proven): big levels ----
__global__ __launch_bounds__(256, 2)
void level128_kernel(const bf16* __restrict__ hprev, bf16* __restrict__ hcur,
                     const float* __restrict__ cprev, float* __restrict__ ccur,
                     const bf16* __restrict__ Uall, const float* __restrict__ Uioub,
                     const float* __restrict__ Ufb)
{
  __shared__ bf16 lsA[128*40];
  __shared__ bf16 lsB[5][64*40];
  const int t = threadIdx.x;
  const int mrow0 = blockIdx.x*128, nblk = blockIdx.y*64;
  const int r = t>>2, kc = (t&3)*8;
  const int lane16 = t&15, quad = (t&63)>>4, w = t>>6;

  f32x4 acc[5][8];
  const f32x4 zero = {0.f,0.f,0.f,0.f};
  #pragma unroll
  for(int o=0;o<5;o++){
    #pragma unroll
    for(int rt=0;rt<8;rt++) acc[o][rt]=zero;
  }

  const bf16* arow0 = hprev + (size_t)(mrow0 + r)*1024;
  const bf16* arow1 = hprev + (size_t)(mrow0 + 64 + r)*1024;
  const int col = nblk + r;
  for (int k0=0;k0<1024;k0+=32){
    *(bf16x8*)&lsA[r*40+kc]      = *(const bf16x8*)&arow0[k0+kc];
    *(bf16x8*)&lsA[(64+r)*40+kc] = *(const bf16x8*)&arow1[k0+kc];
    #pragma unroll
    for(int g=0;g<5;g++)
      *(bf16x8*)&lsB[g][r*40+kc] = *(const bf16x8*)&Uall[(size_t)(g*512+col)*1024 + k0+kc];
    __syncthreads();
    bf16x8 bfrag[5];
    #pragma unroll
    for(int g=0;g<5;g++) bfrag[g] = *(const bf16x8*)&lsB[g][(w*16+lane16)*40 + quad*8];
    #pragma unroll
    for(int rt=0;rt<8;rt++){
      bf16x8 a = *(const bf16x8*)&lsA[(rt*16+lane16)*40 + quad*8];
      #pragma unroll
      for(int g=0;g<5;g++)
        acc[g][rt] = __builtin_amdgcn_mfma_f32_16x16x32_bf16(a, bfrag[g], acc[g][rt], 0,0,0);
    }
    __syncthreads();
  }
  const int j = nblk + w*16 + lane16;
  const float bi =Uioub[j], bo=Uioub[512+j], bu=Uioub[1024+j];
  const float bfl=Ufb[j],   bfr=Ufb[512+j];
  #pragma unroll
  for(int rt=0;rt<8;rt++){
    #pragma unroll
    for(int reg=0;reg<4;reg++){
      const int row = mrow0 + rt*16 + quad*4 + reg;
      float iv=acc[0][rt][reg]+bi, ov=acc[1][rt][reg]+bo, uv=acc[2][rt][reg]+bu;
      float fl=acc[3][rt][reg]+bfl, fr=acc[4][rt][reg]+bfr;
      float cl = cprev[((size_t)row*2  )*512 + j];
      float cr = cprev[((size_t)row*2+1)*512 + j];
      float cf = sigm(fl)*cl + sigm(fr)*cr;
      float c  = sigm(iv)*tanh_f(uv) + cf;
      float h  = sigm(ov)*tanh_f(c);
      ccur[(size_t)row*512 + j] = c;
      hcur[(size_t)row*512 + j] = (bf16)h;
    }
  }
}

// ---- logits: out[node*5+c] = h_row . lin_w[c] + lin_b[c] ----
__global__ __launch_bounds__(256)
void logits_kernel(const bf16* __restrict__ h, const float* __restrict__ linw,
                   const float* __restrict__ linb, float* __restrict__ out,
                   int rowbase, int lgm, int mask, int off){
  const int row = blockIdx.x*4 + (threadIdx.x>>6);
  const int l = threadIdx.x & 63;
  bf16x8 hv = *(const bf16x8*)(h + (size_t)row*512 + l*8);
  float hf[8];
  #pragma unroll
  for(int jj=0;jj<8;jj++) hf[jj] = (float)hv[jj];
  float s[5];
  #pragma unroll
  for(int c=0;c<5;c++){
    const f32x4 w0 = *(const f32x4*)(linw + c*512 + l*8);
    const f32x4 w1 = *(const f32x4*)(linw + c*512 + l*8 + 4);
    float a = 0.f;
    #pragma unroll
    for(int jj=0;jj<4;jj++) a += hf[jj]*w0[jj] + hf[4+jj]*w1[jj];
    s[c]=a;
  }
  #pragma unroll
  for(int o=32;o>0;o>>=1){
    #pragma unroll
    for(int c=0;c<5;c++) s[c] += __shfl_down(s[c], o, 64);
  }
  if (l==0){
    const int g = rowbase + row;
    const int node = (g>>lgm)*511 + off + (g&mask);
    #pragma unroll
    for(int c=0;c<5;c++) out[(size_t)node*5+c] = s[c] + linb[c];
  }
}

__global__ void zero_out(float* out, int n){
  int i = blockIdx.x*256 + threadIdx.x;
  if (i < n) out[i] = 0.f;
}

extern "C" void kernel_launch(void* const* d_in, const int* in_sizes, int n_in,
                              void* d_out, int out_size, void* d_ws, size_t ws_size,
                              hipStream_t stream)
{
  const int*   wordid = (const int*)d_in[0];
  const float* emb    = (const float*)d_in[1];
  const float* Wiou   = (const float*)d_in[2];
  const float* Wioub  = (const float*)d_in[3];
  const float* Uiou   = (const float*)d_in[4];
  const float* Uioub  = (const float*)d_in[5];
  const float* Uf     = (const float*)d_in[6];
  const float* Ufb    = (const float*)d_in[7];
  const float* linw   = (const float*)d_in[8];
  const float* linb   = (const float*)d_in[9];
  float* out = (float*)d_out;

  // ---- fixed-region layout (R7) ----
  const size_t oWPD  = 0;
  const size_t oUALL = oWPD  + (size_t)1536*320*2;
  const size_t oEMB  = oUALL + (size_t)2560*1024*2;
  const size_t oH1   = oEMB  + (size_t)32000*320*2;
  const size_t oC1   = oH1   + (size_t)32768*512*2;
  const size_t oH0   = oC1   + (size_t)32768*512*4;
  size_t R0 = 0;
  {
    const size_t t2 = oH0 + (size_t)32768*512*(2+4);   // 228.0 MB
    const size_t t4 = oH0 + (size_t)16384*512*(2+4);   // 177.7 MB
    const size_t t8 = oH0 + (size_t) 8192*512*(2+4);   // 152.5 MB
    if      (ws_size >= t2) R0 = 32768;
    else if (ws_size >= t4) R0 = 16384;
    else if (ws_size >= t8) R0 = 8192;
  }
  if (R0 == 0){
    zero_out<<<(out_size+255)/256, 256, 0, stream>>>(out, out_size);
    return;
  }

  char* ws = (char*)d_ws;
  bf16*  Wpad = (bf16*)(ws + oWPD);
  bf16*  Uall = (bf16*)(ws + oUALL);
  bf16*  embp = (bf16*)(ws + oEMB);
  bf16*  h1   = (bf16*)(ws + oH1);
  float* c1   = (float*)(ws + oC1);
  bf16*  h0   = (bf16*)(ws + oH0);
  float* c0   = (float*)(ws + oH0 + R0*1024);

  cvt_pad_w<<<1536, 320, 0, stream>>>(Wiou, Wpad);
  cvt_u<<<(2560*1024+255)/256, 256, 0, stream>>>(Uiou, Uf, Uall);
  cvt_emb<<<32000, 320, 0, stream>>>(emb, embp);

  const int offs[9] = {0,256,384,448,480,496,504,508,510};
  const int nchunk = (int)(65536 / R0);

  // ---- leaf + level-1, chunked through h0/c0 scratch ----
  for (int ch = 0; ch < nchunk; ch++){
    const int* wid = wordid + (size_t)ch*R0;
    leaf128_kernel<<<dim3((int)(R0/128), 8), 256, 0, stream>>>(wid, embp, Wpad, Wioub,
                                                               h0, c0);
    logits_kernel<<<(int)(R0/4), 256, 0, stream>>>(h0, linw, linb, out,
                                                   (int)(ch*R0), 8, 255, 0);
    bf16*  h1c = h1 + (size_t)ch*(R0/2)*512;
    float* c1c = c1 + (size_t)ch*(R0/2)*512;
    const int orows = (int)(R0/2);
    level128_kernel<<<dim3(orows/128, 8), 256, 0, stream>>>(h0, h1c, c0, c1c,
                                                            Uall, Uioub, Ufb);
  }
  logits_kernel<<<32768/4, 256, 0, stream>>>(h1, linw, linb, out, 0, 7, 127, offs[1]);

  // ---- levels 2..8: ping-pong h1/c1 <-> h0/c0 regions ----
  for (int lv = 2; lv <= 8; lv++){
    const int rows = 65536 >> lv;
    const bf16*  hin  = (lv & 1) ? h0 : h1;
    bf16*        hout = (lv & 1) ? h1 : h0;
    const float* cin  = (lv & 1) ? c0 : c1;
    float*       cout = (lv & 1) ? c1 : c0;
    if (rows >= 4096)
      level128_kernel<<<dim3(rows/128, 8), 256, 0, stream>>>(hin, hout, cin, cout,
                                                             Uall, Uioub, Ufb);
    else
      level_kernel<<<dim3(rows/64, 8), 256, 0, stream>>>(hin, hout, cin, cout,
                                                         Uall, Uioub, Ufb);
    logits_kernel<<<rows/4, 256, 0, stream>>>(hout, linw, linb, out,
                                              0, 8-lv, (256>>lv)-1, offs[lv]);
  }
}